// Round 1
// baseline (137.332 us; speedup 1.0000x reference)
//
#include <hip/hip_runtime.h>

// Shapes (fixed by the problem)
#define Bn 8
#define Tn 2048
#define Cn 1024
#define Hn 128
#define Mn (Bn*Tn)   // 16384

typedef __attribute__((ext_vector_type(4))) float f32x4;
typedef __attribute__((ext_vector_type(8))) short s16x8;
typedef __attribute__((ext_vector_type(4))) int i32x4;

__device__ __forceinline__ unsigned short f2bf(float f) {
  union { float f; unsigned u; } v; v.f = f;
  unsigned r = v.u + 0x7FFFu + ((v.u >> 16) & 1u);   // RNE, matches v_cvt
  return (unsigned short)(r >> 16);
}

// ---------------------------------------------------------------------------
// Kernel 1: W [C,H] fp32 -> Wt [3][H][C] bf16 (transposed; Wq scaled by 1/32)
// slot 0 = Wq*1/32, slot 1 = Wk, slot 2 = Wv
// ---------------------------------------------------------------------------
__global__ __launch_bounds__(256) void prep_wt(const float* __restrict__ Wq,
                                               const float* __restrict__ Wk,
                                               const float* __restrict__ Wv,
                                               unsigned short* __restrict__ Wt) {
  __shared__ float tile[64][33];
  const int w = blockIdx.z;
  const float* W = (w == 0) ? Wq : (w == 1) ? Wk : Wv;
  const float scale = (w == 0) ? 0.03125f : 1.0f;   // C^-0.5 folded into Wq (exact pow2)
  const int c0 = blockIdx.x * 64, h0 = blockIdx.y * 32;
  const int tid = threadIdx.x;
  const int hl = tid & 31, cg = tid >> 5;
#pragma unroll
  for (int i = 0; i < 8; i++) {
    int cl = cg * 8 + i;
    tile[cl][hl] = W[(c0 + cl) * Hn + h0 + hl];    // coalesced read
  }
  __syncthreads();
  const int cl2 = tid & 63, hg = tid >> 6;
#pragma unroll
  for (int i = 0; i < 8; i++) {
    int hl2 = hg * 8 + i;
    Wt[(size_t)(w * Hn + h0 + hl2) * Cn + c0 + cl2] = f2bf(tile[cl2][hl2] * scale); // coalesced write
  }
}

// ---------------------------------------------------------------------------
// Kernel 2: qkv[w] = x @ W_w   (BM=128, BN=128=H, BK=64, 4 waves, bf16 MFMA)
// A staged fp32->bf16 in-kernel; both LDS tiles XOR-swizzled (16B chunk ^ row&7)
// ---------------------------------------------------------------------------
__global__ __launch_bounds__(256) void proj_gemm(const float* __restrict__ x,
                                                 const unsigned short* __restrict__ Wt,
                                                 unsigned short* __restrict__ qkv) {
  __shared__ __align__(16) unsigned short Al[128 * 64];
  __shared__ __align__(16) unsigned short Bl[128 * 64];
  const int w = blockIdx.y;
  const int bm = blockIdx.x * 128;
  const int tid = threadIdx.x;
  const int lane = tid & 63, wave = tid >> 6;
  const int wm = wave >> 1, wn = wave & 1;
  const int l15 = lane & 15, lg = lane >> 4;
  const unsigned short* Wtw = Wt + (size_t)w * (Hn * Cn);
  f32x4 acc[4][4];
#pragma unroll
  for (int i = 0; i < 4; i++)
#pragma unroll
    for (int j = 0; j < 4; j++) acc[i][j] = (f32x4){0.f, 0.f, 0.f, 0.f};

  for (int kk = 0; kk < Cn; kk += 64) {
    __syncthreads();
    // stage A: x fp32 -> bf16, swizzled
#pragma unroll
    for (int c = 0; c < 4; c++) {
      int q = tid + c * 256;
      int row = q >> 3, sl = q & 7;
      const float* g = x + (size_t)(bm + row) * Cn + kk + sl * 8;
      float4 v0 = *(const float4*)g;
      float4 v1 = *(const float4*)(g + 4);
      s16x8 pk;
      pk[0] = (short)f2bf(v0.x); pk[1] = (short)f2bf(v0.y);
      pk[2] = (short)f2bf(v0.z); pk[3] = (short)f2bf(v0.w);
      pk[4] = (short)f2bf(v1.x); pk[5] = (short)f2bf(v1.y);
      pk[6] = (short)f2bf(v1.z); pk[7] = (short)f2bf(v1.w);
      *(s16x8*)&Al[row * 64 + ((sl ^ (row & 7)) << 3)] = pk;
    }
    // stage B (already bf16, B^T layout), swizzled
#pragma unroll
    for (int c = 0; c < 4; c++) {
      int q = tid + c * 256;
      int n = q >> 3, sl = q & 7;
      i32x4 v = *(const i32x4*)(Wtw + (size_t)n * Cn + kk + sl * 8);
      *(i32x4*)&Bl[n * 64 + ((sl ^ (n & 7)) << 3)] = v;
    }
    __syncthreads();
#pragma unroll
    for (int k2 = 0; k2 < 2; k2++) {
      s16x8 aF[4], bF[4];
#pragma unroll
      for (int mi = 0; mi < 4; mi++) {
        int row = wm * 64 + mi * 16 + l15;
        aF[mi] = *(const s16x8*)&Al[row * 64 + (((k2 * 4 + lg) ^ (row & 7)) << 3)];
      }
#pragma unroll
      for (int ni = 0; ni < 4; ni++) {
        int n = wn * 64 + ni * 16 + l15;
        bF[ni] = *(const s16x8*)&Bl[n * 64 + (((k2 * 4 + lg) ^ (n & 7)) << 3)];
      }
#pragma unroll
      for (int mi = 0; mi < 4; mi++)
#pragma unroll
        for (int ni = 0; ni < 4; ni++)
          acc[mi][ni] = __builtin_amdgcn_mfma_f32_16x16x32_bf16(aF[mi], bF[ni], acc[mi][ni], 0, 0, 0);
    }
  }
  unsigned short* o = qkv + (size_t)w * ((size_t)Mn * Hn);
#pragma unroll
  for (int mi = 0; mi < 4; mi++)
#pragma unroll
    for (int ni = 0; ni < 4; ni++)
#pragma unroll
      for (int r = 0; r < 4; r++) {
        int row = bm + wm * 64 + mi * 16 + lg * 4 + r;   // C/D: row=(lane>>4)*4+reg
        int col = wn * 64 + ni * 16 + l15;               //      col=lane&15
        o[(size_t)row * Hn + col] = f2bf(acc[mi][ni][r]);
      }
}

// ---------------------------------------------------------------------------
// Kernel 3: causal flash attention. 512 blocks x 2 waves; 32 q-rows per block
// (16/wave), KVBLK=32. Heavy blocks dispatched first (LPT).
// ---------------------------------------------------------------------------
__global__ __launch_bounds__(128) void attn_fwd(const unsigned short* __restrict__ qkv,
                                                float* __restrict__ out) {
  __shared__ __align__(16) unsigned short Kl[32 * 136];   // [kv][h], pad 8
  __shared__ __align__(16) unsigned short Vl[128 * 56];   // transposed [h][kv], pad 24
  __shared__ __align__(16) unsigned short Pl[2 * 16 * 48];
  const int bid = blockIdx.x;
  const int b = bid & 7;
  const int qt = 63 - (bid >> 3);          // heavy (late) q-tiles first
  const int tid = threadIdx.x;
  const int lane = tid & 63, wv = tid >> 6;
  const int l15 = lane & 15, lg = lane >> 4;
  const unsigned short* qb = qkv + (size_t)b * (Tn * Hn);
  const unsigned short* kb = qkv + (size_t)(Mn * Hn) + (size_t)b * (Tn * Hn);
  const unsigned short* vb = qkv + (size_t)2 * (Mn * Hn) + (size_t)b * (Tn * Hn);
  unsigned short* Pw = Pl + wv * (16 * 48);
  const int qrow0 = qt * 32 + wv * 16;

  // Q fragments, registers (A-operand: row=lane&15, k=(lane>>4)*8+j)
  s16x8 qf[4];
#pragma unroll
  for (int c = 0; c < 4; c++)
    qf[c] = *(const s16x8*)(qb + (size_t)(qrow0 + l15) * Hn + c * 32 + lg * 8);

  f32x4 o_[8];
#pragma unroll
  for (int i = 0; i < 8; i++) o_[i] = (f32x4){0.f, 0.f, 0.f, 0.f};
  float m_[4], l_[4];
#pragma unroll
  for (int r = 0; r < 4; r++) { m_[r] = -1e30f; l_[r] = 0.f; }

  const int nt = qt + 1;
  for (int t = 0; t < nt; t++) {
    const int kvb = t * 32;
    __syncthreads();                       // protect K/V vs prev iter's reads
    // stage K [32][128] -> Kl
#pragma unroll
    for (int it = 0; it < 4; it++) {
      int q = it * 128 + tid;
      int kv = q >> 4, h0 = (q & 15) << 3;
      i32x4 v = *(const i32x4*)(kb + (size_t)(kvb + kv) * Hn + h0);
      *(i32x4*)&Kl[kv * 136 + h0] = v;
    }
    // stage V transposed -> Vl[h][kv] (b32 pair writes)
#pragma unroll
    for (int it = 0; it < 2; it++) {
      int pq = it * 128 + tid;
      int kv2 = (pq & 15) << 1, h0 = (pq >> 4) << 3;
      const unsigned short* s0 = vb + (size_t)(kvb + kv2) * Hn + h0;
      i32x4 a = *(const i32x4*)s0;
      i32x4 bb = *(const i32x4*)(s0 + Hn);
      const unsigned short* pa = (const unsigned short*)&a;
      const unsigned short* pb = (const unsigned short*)&bb;
#pragma unroll
      for (int i = 0; i < 8; i++) {
        unsigned val = (unsigned)pa[i] | ((unsigned)pb[i] << 16);
        *(unsigned*)&Vl[(h0 + i) * 56 + kv2] = val;
      }
    }
    __syncthreads();
    // S = Q K^T  (scale already folded into q)
    f32x4 s[2];
#pragma unroll
    for (int nb = 0; nb < 2; nb++) {
      s[nb] = (f32x4){0.f, 0.f, 0.f, 0.f};
#pragma unroll
      for (int c = 0; c < 4; c++) {
        s16x8 kf = *(const s16x8*)&Kl[(nb * 16 + l15) * 136 + c * 32 + lg * 8];
        s[nb] = __builtin_amdgcn_mfma_f32_16x16x32_bf16(qf[c], kf, s[nb], 0, 0, 0);
      }
    }
    // causal mask — provably only the last tile touches the diagonal
    if (t == nt - 1) {
#pragma unroll
      for (int nb = 0; nb < 2; nb++)
#pragma unroll
        for (int r = 0; r < 4; r++) {
          int kvg = kvb + nb * 16 + l15;
          int qg = qrow0 + lg * 4 + r;
          if (kvg > qg) s[nb][r] = -1e30f;
        }
    }
    // online softmax (rows live in (lane>>4)*4+reg; cols across lanes 0..15)
    float pmax[4], sc[4], rs[4];
#pragma unroll
    for (int r = 0; r < 4; r++) pmax[r] = fmaxf(s[0][r], s[1][r]);
#pragma unroll
    for (int msk = 1; msk <= 8; msk <<= 1)
#pragma unroll
      for (int r = 0; r < 4; r++) pmax[r] = fmaxf(pmax[r], __shfl_xor(pmax[r], msk));
#pragma unroll
    for (int r = 0; r < 4; r++) {
      float mn = fmaxf(m_[r], pmax[r]);
      sc[r] = __expf(m_[r] - mn);
      m_[r] = mn;
      rs[r] = 0.f;
    }
#pragma unroll
    for (int nb = 0; nb < 2; nb++)
#pragma unroll
      for (int r = 0; r < 4; r++) {
        float p = __expf(s[nb][r] - m_[r]);
        s[nb][r] = p;
        rs[r] += p;
      }
#pragma unroll
    for (int msk = 1; msk <= 8; msk <<= 1)
#pragma unroll
      for (int r = 0; r < 4; r++) rs[r] += __shfl_xor(rs[r], msk);
#pragma unroll
    for (int r = 0; r < 4; r++) l_[r] = l_[r] * sc[r] + rs[r];
#pragma unroll
    for (int hf = 0; hf < 8; hf++)
#pragma unroll
      for (int r = 0; r < 4; r++) o_[hf][r] *= sc[r];
    // P -> LDS (wave-private; same-wave DS ordering is in-order)
#pragma unroll
    for (int nb = 0; nb < 2; nb++)
#pragma unroll
      for (int r = 0; r < 4; r++)
        Pw[(lg * 4 + r) * 48 + nb * 16 + l15] = f2bf(s[nb][r]);
    // PV
    s16x8 pf = *(const s16x8*)&Pw[l15 * 48 + lg * 8];
#pragma unroll
    for (int hf = 0; hf < 8; hf++) {
      s16x8 vf = *(const s16x8*)&Vl[(hf * 16 + l15) * 56 + lg * 8];
      o_[hf] = __builtin_amdgcn_mfma_f32_16x16x32_bf16(pf, vf, o_[hf], 0, 0, 0);
    }
  }
  // epilogue: normalize + store fp32
#pragma unroll
  for (int hf = 0; hf < 8; hf++)
#pragma unroll
    for (int r = 0; r < 4; r++) {
      int qg = qrow0 + lg * 4 + r;
      out[(size_t)(b * Tn + qg) * Hn + hf * 16 + l15] = o_[hf][r] / l_[r];
    }
}

// ---------------------------------------------------------------------------
extern "C" void kernel_launch(void* const* d_in, const int* in_sizes, int n_in,
                              void* d_out, int out_size, void* d_ws, size_t ws_size,
                              hipStream_t stream) {
  const float* x  = (const float*)d_in[0];
  const float* Wk = (const float*)d_in[1];
  const float* Wq = (const float*)d_in[2];
  const float* Wv = (const float*)d_in[3];
  float* out = (float*)d_out;

  char* ws = (char*)d_ws;
  unsigned short* Wt  = (unsigned short*)ws;                 // 3*128*1024*2 = 786432 B
  unsigned short* qkv = (unsigned short*)(ws + 786432);      // 3*16384*128*2 = 12.6 MB

  prep_wt<<<dim3(16, 4, 3), 256, 0, stream>>>(Wq, Wk, Wv, Wt);
  proj_gemm<<<dim3(128, 3), 256, 0, stream>>>(x, Wt, qkv);
  attn_fwd<<<512, 128, 0, stream>>>(qkv, out);
}

// Round 2
// 124.599 us; speedup vs baseline: 1.1022x; 1.1022x over previous
//
#include <hip/hip_runtime.h>
#include <type_traits>

// Shapes (fixed by the problem)
#define Bn 8
#define Tn 2048
#define Cn 1024
#define Hn 128
#define Mn (Bn*Tn)   // 16384

typedef __attribute__((ext_vector_type(4))) float f32x4;
typedef __attribute__((ext_vector_type(8))) short s16x8;
typedef __attribute__((ext_vector_type(4))) int i32x4;

__device__ __forceinline__ unsigned short f2bf(float f) {
  union { float f; unsigned u; } v; v.f = f;
  unsigned r = v.u + 0x7FFFu + ((v.u >> 16) & 1u);   // RNE, matches v_cvt
  return (unsigned short)(r >> 16);
}

// ---------------------------------------------------------------------------
// Kernel 1: W [C,H] fp32 -> Wt [3][H][C] bf16 (transposed; Wq scaled by 1/32)
// ---------------------------------------------------------------------------
__global__ __launch_bounds__(256) void prep_wt(const float* __restrict__ Wq,
                                               const float* __restrict__ Wk,
                                               const float* __restrict__ Wv,
                                               unsigned short* __restrict__ Wt) {
  __shared__ float tile[64][33];
  const int w = blockIdx.z;
  const float* W = (w == 0) ? Wq : (w == 1) ? Wk : Wv;
  const float scale = (w == 0) ? 0.03125f : 1.0f;   // C^-0.5 folded into Wq (exact pow2)
  const int c0 = blockIdx.x * 64, h0 = blockIdx.y * 32;
  const int tid = threadIdx.x;
  const int hl = tid & 31, cg = tid >> 5;
#pragma unroll
  for (int i = 0; i < 8; i++) {
    int cl = cg * 8 + i;
    tile[cl][hl] = W[(c0 + cl) * Hn + h0 + hl];
  }
  __syncthreads();
  const int cl2 = tid & 63, hg = tid >> 6;
#pragma unroll
  for (int i = 0; i < 8; i++) {
    int hl2 = hg * 8 + i;
    Wt[(size_t)(w * Hn + h0 + hl2) * Cn + c0 + cl2] = f2bf(tile[cl2][hl2] * scale);
  }
}

// ---------------------------------------------------------------------------
// Kernel 2: qkv projections. q,k written [b][t][h]; v written TRANSPOSED
// [b][h][t] so attention can load V^T B-fragments directly from global.
// ---------------------------------------------------------------------------
__global__ __launch_bounds__(256) void proj_gemm(const float* __restrict__ x,
                                                 const unsigned short* __restrict__ Wt,
                                                 unsigned short* __restrict__ qkv) {
  __shared__ __align__(16) unsigned short Al[128 * 64];
  __shared__ __align__(16) unsigned short Bl[128 * 64];
  const int w = blockIdx.y;
  const int bm = blockIdx.x * 128;
  const int tid = threadIdx.x;
  const int lane = tid & 63, wave = tid >> 6;
  const int wm = wave >> 1, wn = wave & 1;
  const int l15 = lane & 15, lg = lane >> 4;
  const unsigned short* Wtw = Wt + (size_t)w * (Hn * Cn);
  f32x4 acc[4][4];
#pragma unroll
  for (int i = 0; i < 4; i++)
#pragma unroll
    for (int j = 0; j < 4; j++) acc[i][j] = (f32x4){0.f, 0.f, 0.f, 0.f};

  for (int kk = 0; kk < Cn; kk += 64) {
    __syncthreads();
#pragma unroll
    for (int c = 0; c < 4; c++) {
      int q = tid + c * 256;
      int row = q >> 3, sl = q & 7;
      const float* g = x + (size_t)(bm + row) * Cn + kk + sl * 8;
      float4 v0 = *(const float4*)g;
      float4 v1 = *(const float4*)(g + 4);
      s16x8 pk;
      pk[0] = (short)f2bf(v0.x); pk[1] = (short)f2bf(v0.y);
      pk[2] = (short)f2bf(v0.z); pk[3] = (short)f2bf(v0.w);
      pk[4] = (short)f2bf(v1.x); pk[5] = (short)f2bf(v1.y);
      pk[6] = (short)f2bf(v1.z); pk[7] = (short)f2bf(v1.w);
      *(s16x8*)&Al[row * 64 + ((sl ^ (row & 7)) << 3)] = pk;
    }
#pragma unroll
    for (int c = 0; c < 4; c++) {
      int q = tid + c * 256;
      int n = q >> 3, sl = q & 7;
      i32x4 v = *(const i32x4*)(Wtw + (size_t)n * Cn + kk + sl * 8);
      *(i32x4*)&Bl[n * 64 + ((sl ^ (n & 7)) << 3)] = v;
    }
    __syncthreads();
#pragma unroll
    for (int k2 = 0; k2 < 2; k2++) {
      s16x8 aF[4], bF[4];
#pragma unroll
      for (int mi = 0; mi < 4; mi++) {
        int row = wm * 64 + mi * 16 + l15;
        aF[mi] = *(const s16x8*)&Al[row * 64 + (((k2 * 4 + lg) ^ (row & 7)) << 3)];
      }
#pragma unroll
      for (int ni = 0; ni < 4; ni++) {
        int n = wn * 64 + ni * 16 + l15;
        bF[ni] = *(const s16x8*)&Bl[n * 64 + (((k2 * 4 + lg) ^ (n & 7)) << 3)];
      }
#pragma unroll
      for (int mi = 0; mi < 4; mi++)
#pragma unroll
        for (int ni = 0; ni < 4; ni++)
          acc[mi][ni] = __builtin_amdgcn_mfma_f32_16x16x32_bf16(aF[mi], bF[ni], acc[mi][ni], 0, 0, 0);
    }
  }
  if (w < 2) {
    unsigned short* o = qkv + (size_t)w * ((size_t)Mn * Hn);
#pragma unroll
    for (int mi = 0; mi < 4; mi++)
#pragma unroll
      for (int ni = 0; ni < 4; ni++)
#pragma unroll
        for (int r = 0; r < 4; r++) {
          int row = bm + wm * 64 + mi * 16 + lg * 4 + r;
          int col = wn * 64 + ni * 16 + l15;
          o[(size_t)row * Hn + col] = f2bf(acc[mi][ni][r]);
        }
  } else {
    // V: write transposed [b][h][t] (2B scatters; absorbed by L2/L3)
    const int bb = bm >> 11;
    const int tl = bm & 2047;
    unsigned short* vt = qkv + (size_t)2 * Mn * Hn + (size_t)bb * (Hn * Tn);
#pragma unroll
    for (int mi = 0; mi < 4; mi++)
#pragma unroll
      for (int ni = 0; ni < 4; ni++)
#pragma unroll
        for (int r = 0; r < 4; r++) {
          int trow = tl + wm * 64 + mi * 16 + lg * 4 + r;
          int h = wn * 64 + ni * 16 + l15;
          vt[(size_t)h * Tn + trow] = f2bf(acc[mi][ni][r]);
        }
  }
}

// ---------------------------------------------------------------------------
// Kernel 3: causal flash attention. 1 wave per block (16 q-rows), no barriers,
// K/V MFMA fragments loaded straight from global (L2/L3-resident) with a
// 1-tile-deep register double buffer. Heavy q-tiles dispatched first.
// ---------------------------------------------------------------------------
__global__ __launch_bounds__(64) void attn_fwd(const unsigned short* __restrict__ qkv,
                                               float* __restrict__ out) {
  __shared__ __align__(16) unsigned short Pl[16 * 40];   // [q][kv], stride 40 shorts
  const int bid = blockIdx.x;
  const int b = bid & 7;
  const int qt = 127 - (bid >> 3);          // heavy (late) q-tiles first
  const int lane = threadIdx.x;
  const int l15 = lane & 15, lg = lane >> 4;
  const unsigned short* qb  = qkv + (size_t)b * (Tn * Hn);
  const unsigned short* kb  = qkv + (size_t)(Mn * Hn) + (size_t)b * (Tn * Hn);
  const unsigned short* vtb = qkv + (size_t)2 * (Mn * Hn) + (size_t)b * (Hn * Tn);
  const int qrow0 = qt * 16;
  const int nt = qt / 2 + 1;                // kv tiles of 32

  // Q fragments (A-operand: m=lane&15, k=(lane>>4)*8+j); scale folded into Wq
  s16x8 qf[4];
#pragma unroll
  for (int c = 0; c < 4; c++)
    qf[c] = *(const s16x8*)(qb + (size_t)(qrow0 + l15) * Hn + c * 32 + lg * 8);

  f32x4 o_[8];
#pragma unroll
  for (int i = 0; i < 8; i++) o_[i] = (f32x4){0.f, 0.f, 0.f, 0.f};
  float m_[4], l_[4];
#pragma unroll
  for (int r = 0; r < 4; r++) { m_[r] = -1e30f; l_[r] = 0.f; }

  // register double-buffered K/V fragments
  s16x8 kf[2][8], vf[2][8];
#pragma unroll
  for (int nb = 0; nb < 2; nb++)
#pragma unroll
    for (int c = 0; c < 4; c++)
      kf[0][nb * 4 + c] = *(const s16x8*)(kb + (size_t)(nb * 16 + l15) * Hn + c * 32 + lg * 8);
#pragma unroll
  for (int hf = 0; hf < 8; hf++)
    vf[0][hf] = *(const s16x8*)(vtb + (size_t)(hf * 16 + l15) * Tn + lg * 8);

  auto body = [&](int t, auto CURC) {
    constexpr int CUR = decltype(CURC)::value;
    constexpr int NXT = CUR ^ 1;
    const int kvb = t * 32;
    const int kvbn = (t + 1 < nt ? t + 1 : t) * 32;   // clamped (redundant last load)
    // prefetch t+1 fragments (issue before any use of CUR)
#pragma unroll
    for (int nb = 0; nb < 2; nb++)
#pragma unroll
      for (int c = 0; c < 4; c++)
        kf[NXT][nb * 4 + c] = *(const s16x8*)(kb + (size_t)(kvbn + nb * 16 + l15) * Hn + c * 32 + lg * 8);
#pragma unroll
    for (int hf = 0; hf < 8; hf++)
      vf[NXT][hf] = *(const s16x8*)(vtb + (size_t)(hf * 16 + l15) * Tn + kvbn + lg * 8);

    // S = Q K^T
    f32x4 s[2];
#pragma unroll
    for (int nb = 0; nb < 2; nb++) {
      s[nb] = (f32x4){0.f, 0.f, 0.f, 0.f};
#pragma unroll
      for (int c = 0; c < 4; c++)
        s[nb] = __builtin_amdgcn_mfma_f32_16x16x32_bf16(qf[c], kf[CUR][nb * 4 + c], s[nb], 0, 0, 0);
    }
    // causal mask — only the final tile touches the diagonal
    if (t == nt - 1) {
#pragma unroll
      for (int nb = 0; nb < 2; nb++)
#pragma unroll
        for (int r = 0; r < 4; r++) {
          int kvg = kvb + nb * 16 + l15;
          int qg = qrow0 + lg * 4 + r;
          if (kvg > qg) s[nb][r] = -1e30f;
        }
    }
    // online softmax (rows in (lane>>4)*4+r, cols across lanes 0..15)
    float pmax[4], sc[4], rs[4];
#pragma unroll
    for (int r = 0; r < 4; r++) pmax[r] = fmaxf(s[0][r], s[1][r]);
#pragma unroll
    for (int msk = 1; msk <= 8; msk <<= 1)
#pragma unroll
      for (int r = 0; r < 4; r++) pmax[r] = fmaxf(pmax[r], __shfl_xor(pmax[r], msk));
#pragma unroll
    for (int r = 0; r < 4; r++) {
      float mn = fmaxf(m_[r], pmax[r]);
      sc[r] = __expf(m_[r] - mn);
      m_[r] = mn;
      rs[r] = 0.f;
    }
#pragma unroll
    for (int nb = 0; nb < 2; nb++)
#pragma unroll
      for (int r = 0; r < 4; r++) {
        float p = __expf(s[nb][r] - m_[r]);
        s[nb][r] = p;
        rs[r] += p;
      }
#pragma unroll
    for (int msk = 1; msk <= 8; msk <<= 1)
#pragma unroll
      for (int r = 0; r < 4; r++) rs[r] += __shfl_xor(rs[r], msk);
#pragma unroll
    for (int r = 0; r < 4; r++) l_[r] = l_[r] * sc[r] + rs[r];
#pragma unroll
    for (int hf = 0; hf < 8; hf++)
#pragma unroll
      for (int r = 0; r < 4; r++) o_[hf][r] *= sc[r];
    // P -> LDS roundtrip (wave-private, in-order)
#pragma unroll
    for (int nb = 0; nb < 2; nb++)
#pragma unroll
      for (int r = 0; r < 4; r++)
        Pl[(lg * 4 + r) * 40 + nb * 16 + l15] = f2bf(s[nb][r]);
    s16x8 pf = *(const s16x8*)&Pl[l15 * 40 + lg * 8];
    // PV
#pragma unroll
    for (int hf = 0; hf < 8; hf++)
      o_[hf] = __builtin_amdgcn_mfma_f32_16x16x32_bf16(pf, vf[CUR][hf], o_[hf], 0, 0, 0);
  };

  for (int t = 0; t < nt; t += 2) {
    body(t, std::integral_constant<int, 0>{});
    if (t + 1 < nt) body(t + 1, std::integral_constant<int, 1>{});
  }

  // epilogue
  float inv[4];
#pragma unroll
  for (int r = 0; r < 4; r++) inv[r] = 1.0f / l_[r];
#pragma unroll
  for (int hf = 0; hf < 8; hf++)
#pragma unroll
    for (int r = 0; r < 4; r++) {
      int qg = qrow0 + lg * 4 + r;
      out[(size_t)(b * Tn + qg) * Hn + hf * 16 + l15] = o_[hf][r] * inv[r];
    }
}

// ---------------------------------------------------------------------------
extern "C" void kernel_launch(void* const* d_in, const int* in_sizes, int n_in,
                              void* d_out, int out_size, void* d_ws, size_t ws_size,
                              hipStream_t stream) {
  const float* x  = (const float*)d_in[0];
  const float* Wk = (const float*)d_in[1];
  const float* Wq = (const float*)d_in[2];
  const float* Wv = (const float*)d_in[3];
  float* out = (float*)d_out;

  char* ws = (char*)d_ws;
  unsigned short* Wt  = (unsigned short*)ws;                 // 3*128*1024*2 = 786432 B
  unsigned short* qkv = (unsigned short*)(ws + 786432);      // 3*16384*128*2 = 12.6 MB

  prep_wt<<<dim3(16, 4, 3), 256, 0, stream>>>(Wq, Wk, Wv, Wt);
  proj_gemm<<<dim3(128, 3), 256, 0, stream>>>(x, Wt, qkv);
  attn_fwd<<<1024, 64, 0, stream>>>(qkv, out);
}

// Round 3
// 97.634 us; speedup vs baseline: 1.4066x; 1.2762x over previous
//
#include <hip/hip_runtime.h>
#include <type_traits>

// Shapes (fixed by the problem)
#define Bn 8
#define Tn 2048
#define Cn 1024
#define Hn 128
#define Mn (Bn*Tn)   // 16384

typedef __attribute__((ext_vector_type(4))) float f32x4;
typedef __attribute__((ext_vector_type(2))) float f32x2;
typedef __attribute__((ext_vector_type(16))) float f32x16;
typedef __attribute__((ext_vector_type(8))) short s16x8;
typedef __attribute__((ext_vector_type(4))) int i32x4;
typedef __attribute__((ext_vector_type(2))) int i32x2;

__device__ __forceinline__ unsigned short f2bf(float f) {
  union { float f; unsigned u; } v; v.f = f;
  unsigned r = v.u + 0x7FFFu + ((v.u >> 16) & 1u);   // RNE
  return (unsigned short)(r >> 16);
}

__device__ __forceinline__ unsigned cvtpk(float lo, float hi) {
  unsigned r;
  asm("v_cvt_pk_bf16_f32 %0, %1, %2" : "=v"(r) : "v"(lo), "v"(hi));
  return r;
}

// swap32(a,b): r0 = {a.lanes[0:31], b.lanes[0:31]}, r1 = {a.lanes[32:63], b.lanes[32:63]}
__device__ __forceinline__ i32x2 swap32(int a, int b) {
#if __has_builtin(__builtin_amdgcn_permlane32_swap)
  return __builtin_amdgcn_permlane32_swap(a, b, false, false);
#else
  int ax = __shfl_xor(a, 32), bx = __shfl_xor(b, 32);
  i32x2 r;
  r[0] = (threadIdx.x & 32) ? bx : a;
  r[1] = (threadIdx.x & 32) ? b : ax;
  return r;
#endif
}

// ---------------------------------------------------------------------------
// Kernel 1: W [C,H] fp32 -> Wt [3][H][C] bf16 (transposed; Wq scaled by 1/32)
// ---------------------------------------------------------------------------
__global__ __launch_bounds__(256) void prep_wt(const float* __restrict__ Wq,
                                               const float* __restrict__ Wk,
                                               const float* __restrict__ Wv,
                                               unsigned short* __restrict__ Wt) {
  __shared__ float tile[64][33];
  const int w = blockIdx.z;
  const float* W = (w == 0) ? Wq : (w == 1) ? Wk : Wv;
  const float scale = (w == 0) ? 0.03125f : 1.0f;   // C^-0.5 folded into Wq (exact pow2)
  const int c0 = blockIdx.x * 64, h0 = blockIdx.y * 32;
  const int tid = threadIdx.x;
  const int hl = tid & 31, cg = tid >> 5;
#pragma unroll
  for (int i = 0; i < 8; i++) {
    int cl = cg * 8 + i;
    tile[cl][hl] = W[(c0 + cl) * Hn + h0 + hl];
  }
  __syncthreads();
  const int cl2 = tid & 63, hg = tid >> 6;
#pragma unroll
  for (int i = 0; i < 8; i++) {
    int hl2 = hg * 8 + i;
    Wt[(size_t)(w * Hn + h0 + hl2) * Cn + c0 + cl2] = f2bf(tile[cl2][hl2] * scale);
  }
}

// ---------------------------------------------------------------------------
// Kernel 2: qkv projections. q,k written [b][t][h]; v written TRANSPOSED [b][h][t].
// ---------------------------------------------------------------------------
__global__ __launch_bounds__(256) void proj_gemm(const float* __restrict__ x,
                                                 const unsigned short* __restrict__ Wt,
                                                 unsigned short* __restrict__ qkv) {
  __shared__ __align__(16) unsigned short Al[128 * 64];
  __shared__ __align__(16) unsigned short Bl[128 * 64];
  const int w = blockIdx.y;
  const int bm = blockIdx.x * 128;
  const int tid = threadIdx.x;
  const int lane = tid & 63, wave = tid >> 6;
  const int wm = wave >> 1, wn = wave & 1;
  const int l15 = lane & 15, lg = lane >> 4;
  const unsigned short* Wtw = Wt + (size_t)w * (Hn * Cn);
  f32x4 acc[4][4];
#pragma unroll
  for (int i = 0; i < 4; i++)
#pragma unroll
    for (int j = 0; j < 4; j++) acc[i][j] = (f32x4){0.f, 0.f, 0.f, 0.f};

  for (int kk = 0; kk < Cn; kk += 64) {
    __syncthreads();
#pragma unroll
    for (int c = 0; c < 4; c++) {
      int q = tid + c * 256;
      int row = q >> 3, sl = q & 7;
      const float* g = x + (size_t)(bm + row) * Cn + kk + sl * 8;
      float4 v0 = *(const float4*)g;
      float4 v1 = *(const float4*)(g + 4);
      s16x8 pk;
      pk[0] = (short)f2bf(v0.x); pk[1] = (short)f2bf(v0.y);
      pk[2] = (short)f2bf(v0.z); pk[3] = (short)f2bf(v0.w);
      pk[4] = (short)f2bf(v1.x); pk[5] = (short)f2bf(v1.y);
      pk[6] = (short)f2bf(v1.z); pk[7] = (short)f2bf(v1.w);
      *(s16x8*)&Al[row * 64 + ((sl ^ (row & 7)) << 3)] = pk;
    }
#pragma unroll
    for (int c = 0; c < 4; c++) {
      int q = tid + c * 256;
      int n = q >> 3, sl = q & 7;
      i32x4 v = *(const i32x4*)(Wtw + (size_t)n * Cn + kk + sl * 8);
      *(i32x4*)&Bl[n * 64 + ((sl ^ (n & 7)) << 3)] = v;
    }
    __syncthreads();
#pragma unroll
    for (int k2 = 0; k2 < 2; k2++) {
      s16x8 aF[4], bF[4];
#pragma unroll
      for (int mi = 0; mi < 4; mi++) {
        int row = wm * 64 + mi * 16 + l15;
        aF[mi] = *(const s16x8*)&Al[row * 64 + (((k2 * 4 + lg) ^ (row & 7)) << 3)];
      }
#pragma unroll
      for (int ni = 0; ni < 4; ni++) {
        int n = wn * 64 + ni * 16 + l15;
        bF[ni] = *(const s16x8*)&Bl[n * 64 + (((k2 * 4 + lg) ^ (n & 7)) << 3)];
      }
#pragma unroll
      for (int mi = 0; mi < 4; mi++)
#pragma unroll
        for (int ni = 0; ni < 4; ni++)
          acc[mi][ni] = __builtin_amdgcn_mfma_f32_16x16x32_bf16(aF[mi], bF[ni], acc[mi][ni], 0, 0, 0);
    }
  }
  if (w < 2) {
    unsigned short* o = qkv + (size_t)w * ((size_t)Mn * Hn);
#pragma unroll
    for (int mi = 0; mi < 4; mi++)
#pragma unroll
      for (int ni = 0; ni < 4; ni++)
#pragma unroll
        for (int r = 0; r < 4; r++) {
          int row = bm + wm * 64 + mi * 16 + lg * 4 + r;
          int col = wn * 64 + ni * 16 + l15;
          o[(size_t)row * Hn + col] = f2bf(acc[mi][ni][r]);
        }
  } else {
    const int bb = bm >> 11;
    const int tl = bm & 2047;
    unsigned short* vt = qkv + (size_t)2 * Mn * Hn + (size_t)bb * (Hn * Tn);
#pragma unroll
    for (int mi = 0; mi < 4; mi++)
#pragma unroll
      for (int ni = 0; ni < 4; ni++)
#pragma unroll
        for (int r = 0; r < 4; r++) {
          int trow = tl + wm * 64 + mi * 16 + lg * 4 + r;
          int h = wn * 64 + ni * 16 + l15;
          vt[(size_t)h * Tn + trow] = f2bf(acc[mi][ni][r]);
        }
  }
}

// ---------------------------------------------------------------------------
// Kernel 3: causal flash attention, swapped 32x32 MFMA, VALU-only softmax,
// KV-split into S chunks. 1 wave/block, 32 q-rows/wave, KVBLK=32, no LDS.
// Writes unnormalized partials (o^T, m, l) to workspace.
// ---------------------------------------------------------------------------
__global__ __launch_bounds__(64, 2) void attn_fwd(const unsigned short* __restrict__ qkv,
                                                  float* __restrict__ o_part,
                                                  float* __restrict__ ml,
                                                  int sshift) {
  const int bid = blockIdx.x;
  const int b = bid & 7;
  const int tmp = bid >> 3;
  const int S = 1 << sshift;
  const int s = tmp & (S - 1);
  const int qt = 63 - (tmp >> sshift);      // heavy q-tiles first
  const int lane = threadIdx.x;
  const int l31 = lane & 31;
  const int hi = lane >> 5;
  const int k8 = hi * 8;                    // per-lane k offset in fragments

  const unsigned short* qb  = qkv + (size_t)b * (Tn * Hn);
  const unsigned short* kb  = qkv + (size_t)(Mn * Hn) + (size_t)b * (Tn * Hn);
  const unsigned short* vtb = qkv + (size_t)2 * (Mn * Hn) + (size_t)b * (Hn * Tn);
  const int qrow0 = qt * 32;
  const int qg = qrow0 + l31;               // this lane's q row

  const int ntt = qt + 1;                   // total kv tiles for this q-tile
  const int lo = (s * ntt) >> sshift;
  const int hiT = ((s + 1) * ntt) >> sshift;

  f32x16 oT[4];
#pragma unroll
  for (int i = 0; i < 4; i++)
#pragma unroll
    for (int r = 0; r < 16; r++) oT[i][r] = 0.f;
  float m_ = -1e30f, l_ = 0.f;

  if (lo < hiT) {
    // Q B-fragments: n=q=l31, k = hs*16 + hi*8 + j
    s16x8 qB[8];
#pragma unroll
    for (int hs = 0; hs < 8; hs++)
      qB[hs] = *(const s16x8*)(qb + (size_t)qg * Hn + hs * 16 + k8);
    // K A-fragments, double-buffered: m=kv=l31, k = hs*16 + hi*8 + j
    s16x8 kA[2][8];
#pragma unroll
    for (int hs = 0; hs < 8; hs++)
      kA[0][hs] = *(const s16x8*)(kb + (size_t)(lo * 32 + l31) * Hn + hs * 16 + k8);

    auto body = [&](int t, auto CURC) {
      constexpr int CUR = decltype(CURC)::value;
      const int kvb = t * 32;
      // V A-fragments for this tile: m=h, k=kv (two 16-kv halves per 32-h slice)
      s16x8 vA[8];
#pragma unroll
      for (int hs = 0; hs < 4; hs++)
#pragma unroll
        for (int c = 0; c < 2; c++)
          vA[hs * 2 + c] = *(const s16x8*)(vtb + (size_t)(hs * 32 + l31) * Tn + kvb + c * 16 + k8);
      // K prefetch for t+1 (clamped)
      const int tn = (t + 1 < hiT) ? t + 1 : t;
#pragma unroll
      for (int hs = 0; hs < 8; hs++)
        kA[CUR ^ 1][hs] = *(const s16x8*)(kb + (size_t)(tn * 32 + l31) * Hn + hs * 16 + k8);

      // S^T = K Q^T : D[kv][q], col=q=l31, row kv=(r&3)+8*(r>>2)+4*hi
      f32x16 sv;
#pragma unroll
      for (int r = 0; r < 16; r++) sv[r] = 0.f;
#pragma unroll
      for (int hs = 0; hs < 8; hs++)
        sv = __builtin_amdgcn_mfma_f32_32x32x16_bf16(kA[CUR][hs], qB[hs], sv, 0, 0, 0);

      // causal mask (diagonal tile only — t==qt occurs only in the last chunk)
      if (t == qt) {
#pragma unroll
        for (int r = 0; r < 16; r++) {
          int kvg = kvb + (r & 3) + 8 * (r >> 2) + 4 * hi;
          if (kvg > qg) sv[r] = -1e30f;
        }
      }
      // tile max: in-register tree + one partner exchange
      float om = sv[0];
#pragma unroll
      for (int r = 1; r < 16; r++) om = fmaxf(om, sv[r]);
      i32x2 mx = swap32(__builtin_bit_cast(int, om), __builtin_bit_cast(int, om));
      float pm = __builtin_bit_cast(float, hi ? mx[0] : mx[1]);
      float tmax = fmaxf(om, pm);
      // deferred rescale (T13, THR=8)
      if (__any(tmax > m_ + 8.f)) {
        float mn = fmaxf(m_, tmax);
        float sc = __expf(m_ - mn);
        m_ = mn; l_ *= sc;
#pragma unroll
        for (int i = 0; i < 4; i++)
#pragma unroll
          for (int r = 0; r < 16; r++) oT[i][r] *= sc;
      }
      // p = exp(s - m_), row-sum
      float osum = 0.f;
#pragma unroll
      for (int r = 0; r < 16; r++) {
        sv[r] = __expf(sv[r] - m_);
        osum += sv[r];
      }
      i32x2 sx = swap32(__builtin_bit_cast(int, osum), __builtin_bit_cast(int, osum));
      float psum = __builtin_bit_cast(float, hi ? sx[0] : sx[1]);
      l_ += osum + psum;
      // pack P to bf16 pairs and exchange halves (T12): 8 cvt_pk + 4 permlane
      unsigned PK[8];
#pragma unroll
      for (int n = 0; n < 8; n++) PK[n] = cvtpk(sv[2 * n], sv[2 * n + 1]);
      i32x2 e0 = swap32((int)PK[0], (int)PK[2]);
      i32x2 e1 = swap32((int)PK[1], (int)PK[3]);
      i32x2 e2 = swap32((int)PK[4], (int)PK[6]);
      i32x2 e3 = swap32((int)PK[5], (int)PK[7]);
      i32x4 w0 = {e0[0], e1[0], e0[1], e1[1]};   // kv 0..15 fragment
      i32x4 w1 = {e2[0], e3[0], e2[1], e3[1]};   // kv 16..31 fragment
      s16x8 pB0 = __builtin_bit_cast(s16x8, w0);
      s16x8 pB1 = __builtin_bit_cast(s16x8, w1);
      // O^T += V^T P^T : D[h][q]
#pragma unroll
      for (int hs = 0; hs < 4; hs++) {
        oT[hs] = __builtin_amdgcn_mfma_f32_32x32x16_bf16(vA[hs * 2 + 0], pB0, oT[hs], 0, 0, 0);
        oT[hs] = __builtin_amdgcn_mfma_f32_32x32x16_bf16(vA[hs * 2 + 1], pB1, oT[hs], 0, 0, 0);
      }
    };

    for (int t = lo; t < hiT; t += 2) {
      body(t, std::integral_constant<int, 0>{});
      if (t + 1 < hiT) body(t + 1, std::integral_constant<int, 1>{});
    }
  }

  // epilogue: write partials. o_part[s][row][h], h = hs*32 + (r&3) + 8*(r>>2) + 4*hi
  float* orow = o_part + (size_t)s * ((size_t)Mn * Hn) + (size_t)(b * Tn + qg) * Hn;
#pragma unroll
  for (int hs = 0; hs < 4; hs++)
#pragma unroll
    for (int g = 0; g < 4; g++) {
      f32x4 st = {oT[hs][4 * g + 0], oT[hs][4 * g + 1], oT[hs][4 * g + 2], oT[hs][4 * g + 3]};
      *(f32x4*)(orow + hs * 32 + g * 8 + hi * 4) = st;
    }
  if (lane < 32) {
    f32x2 w = {m_, l_};
    *(f32x2*)(ml + (size_t)s * (Mn * 2) + (size_t)(b * Tn + qg) * 2) = w;
  }
}

// ---------------------------------------------------------------------------
// Kernel 4: combine KV-split partials. One block per 2 rows.
// ---------------------------------------------------------------------------
__global__ __launch_bounds__(256) void combine(const float* __restrict__ o_part,
                                               const float* __restrict__ ml,
                                               float* __restrict__ out, int S) {
  const int q = blockIdx.x * 2 + (threadIdx.x >> 7);
  const int h = threadIdx.x & 127;
  float M = -1e30f;
  for (int s = 0; s < S; s++) M = fmaxf(M, ml[(size_t)s * (Mn * 2) + q * 2]);
  float L = 0.f, acc = 0.f;
  for (int s = 0; s < S; s++) {
    float ms = ml[(size_t)s * (Mn * 2) + q * 2];
    float ls = ml[(size_t)s * (Mn * 2) + q * 2 + 1];
    float w = __expf(ms - M);
    L += ls * w;
    acc += o_part[(size_t)s * ((size_t)Mn * Hn) + (size_t)q * Hn + h] * w;
  }
  out[(size_t)q * Hn + h] = acc / L;
}

// ---------------------------------------------------------------------------
extern "C" void kernel_launch(void* const* d_in, const int* in_sizes, int n_in,
                              void* d_out, int out_size, void* d_ws, size_t ws_size,
                              hipStream_t stream) {
  const float* x  = (const float*)d_in[0];
  const float* Wk = (const float*)d_in[1];
  const float* Wq = (const float*)d_in[2];
  const float* Wv = (const float*)d_in[3];
  float* out = (float*)d_out;

  char* ws = (char*)d_ws;
  const size_t wt_b  = 786432;                      // 3*128*1024*2
  const size_t qkv_b = (size_t)3 * Mn * Hn * 2;     // 12.58 MB
  const size_t base  = wt_b + qkv_b;
  const size_t per   = (size_t)Mn * Hn * 4 + (size_t)Mn * 8;  // o_part + ml per split
  int sshift = (ws_size >= base + 4 * per) ? 2 : (ws_size >= base + 2 * per) ? 1 : 0;
  const int S = 1 << sshift;

  unsigned short* Wt  = (unsigned short*)ws;
  unsigned short* qkv = (unsigned short*)(ws + wt_b);
  float* o_part = (float*)(ws + base);
  float* mlp    = (float*)(ws + base + (size_t)S * Mn * Hn * 4);

  prep_wt<<<dim3(16, 4, 3), 256, 0, stream>>>(Wq, Wk, Wv, Wt);
  proj_gemm<<<dim3(128, 3), 256, 0, stream>>>(x, Wt, qkv);
  attn_fwd<<<64 * S * 8, 64, 0, stream>>>(qkv, o_part, mlp, sshift);
  combine<<<Mn / 2, 256, 0, stream>>>(o_part, mlp, out, S);
}

// Round 4
// 92.648 us; speedup vs baseline: 1.4823x; 1.0538x over previous
//
#include <hip/hip_runtime.h>
#include <type_traits>

// Shapes (fixed by the problem)
#define Bn 8
#define Tn 2048
#define Cn 1024
#define Hn 128
#define Mn (Bn*Tn)   // 16384

typedef __attribute__((ext_vector_type(4))) float f32x4;
typedef __attribute__((ext_vector_type(2))) float f32x2;
typedef __attribute__((ext_vector_type(16))) float f32x16;
typedef __attribute__((ext_vector_type(8))) short s16x8;
typedef __attribute__((ext_vector_type(4))) int i32x4;
typedef __attribute__((ext_vector_type(2))) int i32x2;
typedef unsigned int u32;

__device__ __forceinline__ unsigned short f2bf(float f) {
  union { float f; unsigned u; } v; v.f = f;
  unsigned r = v.u + 0x7FFFu + ((v.u >> 16) & 1u);   // RNE
  return (unsigned short)(r >> 16);
}

__device__ __forceinline__ unsigned cvtpk(float lo, float hi) {
  unsigned r;
  asm("v_cvt_pk_bf16_f32 %0, %1, %2" : "=v"(r) : "v"(lo), "v"(hi));
  return r;
}

// swap32(a,b): r0 = {a.lanes[0:31], b.lanes[0:31]}, r1 = {a.lanes[32:63], b.lanes[32:63]}
__device__ __forceinline__ i32x2 swap32(int a, int b) {
#if __has_builtin(__builtin_amdgcn_permlane32_swap)
  return __builtin_amdgcn_permlane32_swap(a, b, false, false);
#else
  int ax = __shfl_xor(a, 32), bx = __shfl_xor(b, 32);
  i32x2 r;
  r[0] = (threadIdx.x & 32) ? bx : a;
  r[1] = (threadIdx.x & 32) ? b : ax;
  return r;
#endif
}

__device__ __forceinline__ void gl_lds16(const void* g, void* l) {
  __builtin_amdgcn_global_load_lds((const __attribute__((address_space(1))) u32*)g,
                                   (__attribute__((address_space(3))) u32*)l, 16, 0, 0);
}

// ---------------------------------------------------------------------------
// Kernel 1: W [C,H] fp32 -> Wt [3][H][C] = [384][1024] bf16 (Wq scaled by 1/32)
// ---------------------------------------------------------------------------
__global__ __launch_bounds__(256) void prep_wt(const float* __restrict__ Wq,
                                               const float* __restrict__ Wk,
                                               const float* __restrict__ Wv,
                                               unsigned short* __restrict__ Wt) {
  __shared__ float tile[64][33];
  const int w = blockIdx.z;
  const float* W = (w == 0) ? Wq : (w == 1) ? Wk : Wv;
  const float scale = (w == 0) ? 0.03125f : 1.0f;   // C^-0.5 folded into Wq (exact pow2)
  const int c0 = blockIdx.x * 64, h0 = blockIdx.y * 32;
  const int tid = threadIdx.x;
  const int hl = tid & 31, cg = tid >> 5;
#pragma unroll
  for (int i = 0; i < 8; i++) {
    int cl = cg * 8 + i;
    tile[cl][hl] = W[(c0 + cl) * Hn + h0 + hl];
  }
  __syncthreads();
  const int cl2 = tid & 63, hg = tid >> 6;
#pragma unroll
  for (int i = 0; i < 8; i++) {
    int hl2 = hg * 8 + i;
    Wt[(size_t)(w * Hn + h0 + hl2) * Cn + c0 + cl2] = f2bf(tile[cl2][hl2] * scale);
  }
}

// ---------------------------------------------------------------------------
// Kernel 2: FUSED QKV projection. BM=64, BN=384 (q|k|v), BK=64, 8 waves,
// 32x32x16 MFMA, 2-phase double-buffered LDS, global_load_lds for B with
// pre-swizzled per-lane source, reg-staged A with cvt_pk. One barrier/step.
// q,k written [b][t][h]; v written transposed [b][h][t].
// ---------------------------------------------------------------------------
__global__ __launch_bounds__(512, 2) void proj_fused(const float* __restrict__ x,
                                                     const unsigned short* __restrict__ Wt,
                                                     unsigned short* __restrict__ qkv) {
  __shared__ __align__(16) unsigned short Abuf[2][64 * 64];    // 16 KB
  __shared__ __align__(16) unsigned short Bbuf[2][384 * 64];   // 96 KB
  const int tid = threadIdx.x;
  const int lane = tid & 63, wv = tid >> 6;   // 8 waves
  const int wm = wv >> 2, wn = wv & 3;        // wave tile: rows wm*32, cols wn*96
  const int l31 = lane & 31, hi = lane >> 5;
  const int bm = blockIdx.x * 64;

  // A-staging geometry (512 threads, 64x64 tile, 8 elems each)
  const int ar = tid >> 3;                    // row 0..63
  const int as = (tid & 7) ^ (ar & 7);        // swizzled source slot

  f32x16 acc[3];
#pragma unroll
  for (int i = 0; i < 3; i++)
#pragma unroll
    for (int r = 0; r < 16; r++) acc[i][r] = 0.f;

  auto stageB = [&](int buf, int kk) {
#pragma unroll
    for (int i = 0; i < 6; i++) {
      int r0 = wv * 48 + i * 8;
      int n = r0 + (lane >> 3);
      const unsigned short* src = Wt + (size_t)n * Cn + kk + (((lane & 7) ^ (n & 7)) << 3);
      gl_lds16(src, &Bbuf[buf][r0 * 64]);     // lds dest wave-uniform; +lane*16B implicit
    }
  };
  auto loadA = [&](int kk, float4& v0, float4& v1) {
    const float* g = x + (size_t)(bm + ar) * Cn + kk + as * 8;
    v0 = *(const float4*)g;
    v1 = *(const float4*)(g + 4);
  };
  auto writeA = [&](int buf, float4 v0, float4 v1) {
    i32x4 w = {(int)cvtpk(v0.x, v0.y), (int)cvtpk(v0.z, v0.w),
               (int)cvtpk(v1.x, v1.y), (int)cvtpk(v1.z, v1.w)};
    *(i32x4*)&Abuf[buf][ar * 64 + ((tid & 7) << 3)] = w;
  };

  // prologue: stage K-step 0
  {
    float4 a0, a1;
    loadA(0, a0, a1);
    stageB(0, 0);
    writeA(0, a0, a1);
  }
  __syncthreads();

#pragma unroll 2
  for (int t = 0; t < 16; t++) {
    const int cur = t & 1, nxt = cur ^ 1;
    const bool more = (t < 15);
    float4 a0, a1;
    if (more) {
      loadA((t + 1) * 64, a0, a1);            // issue early (T14)
      stageB(nxt, (t + 1) * 64);              // async global->LDS, in flight over MFMA
    }
    const unsigned short* Ab = Abuf[cur];
    const unsigned short* Bb = Bbuf[cur];
    s16x8 aF[4];
    const int arow = wm * 32 + l31;
#pragma unroll
    for (int ks = 0; ks < 4; ks++)
      aF[ks] = *(const s16x8*)&Ab[arow * 64 + (((ks * 2 + hi) ^ (arow & 7)) << 3)];
#pragma unroll
    for (int ks = 0; ks < 4; ks++)
#pragma unroll
      for (int ni = 0; ni < 3; ni++) {
        int brow = (wn * 3 + ni) * 32 + l31;
        s16x8 bF = *(const s16x8*)&Bb[brow * 64 + (((ks * 2 + hi) ^ (brow & 7)) << 3)];
        acc[ni] = __builtin_amdgcn_mfma_f32_32x32x16_bf16(aF[ks], bF, acc[ni], 0, 0, 0);
      }
    if (more) {
      writeA(nxt, a0, a1);                    // waits vmcnt for A loads only
      __syncthreads();                        // drains B gload_lds + publishes A
    }
  }

  // epilogue: D layout col=l31, row=(r&3)+8*(r>>2)+4*hi
#pragma unroll
  for (int ni = 0; ni < 3; ni++) {
    const int nt = wn * 3 + ni;
    if (nt < 8) {                             // q (nt 0-3) / k (nt 4-7): [b][t][h]
      const int w = nt >> 2;
      const int h = (nt & 3) * 32 + l31;
      unsigned short* o = qkv + (size_t)w * ((size_t)Mn * Hn);
#pragma unroll
      for (int r = 0; r < 16; r++) {
        int m = bm + wm * 32 + (r & 3) + 8 * (r >> 2) + 4 * hi;
        o[(size_t)m * Hn + h] = f2bf(acc[ni][r]);
      }
    } else {                                  // v: transposed [b][h][t]
      const int h = (nt - 8) * 32 + l31;
      const int bb = bm >> 11;
      const int tl0 = (bm & 2047) + wm * 32;
      unsigned short* vt = qkv + (size_t)2 * Mn * Hn + (size_t)bb * (Hn * Tn) + (size_t)h * Tn;
#pragma unroll
      for (int r = 0; r < 16; r++)
        vt[tl0 + (r & 3) + 8 * (r >> 2) + 4 * hi] = f2bf(acc[ni][r]);
    }
  }
}

// ---------------------------------------------------------------------------
// Kernel 3: causal flash attention, swapped 32x32 MFMA, VALU-only softmax,
// KV-split into S chunks. 1 wave/block, 32 q-rows/wave, KVBLK=32, no LDS.
// ---------------------------------------------------------------------------
__global__ __launch_bounds__(64, 2) void attn_fwd(const unsigned short* __restrict__ qkv,
                                                  float* __restrict__ o_part,
                                                  float* __restrict__ ml,
                                                  int sshift) {
  const int bid = blockIdx.x;
  const int b = bid & 7;
  const int tmp = bid >> 3;
  const int S = 1 << sshift;
  const int s = tmp & (S - 1);
  const int qt = 63 - (tmp >> sshift);      // heavy q-tiles first
  const int lane = threadIdx.x;
  const int l31 = lane & 31;
  const int hi = lane >> 5;
  const int k8 = hi * 8;

  const unsigned short* qb  = qkv + (size_t)b * (Tn * Hn);
  const unsigned short* kb  = qkv + (size_t)(Mn * Hn) + (size_t)b * (Tn * Hn);
  const unsigned short* vtb = qkv + (size_t)2 * (Mn * Hn) + (size_t)b * (Hn * Tn);
  const int qrow0 = qt * 32;
  const int qg = qrow0 + l31;

  const int ntt = qt + 1;
  const int lo = (s * ntt) >> sshift;
  const int hiT = ((s + 1) * ntt) >> sshift;

  f32x16 oT[4];
#pragma unroll
  for (int i = 0; i < 4; i++)
#pragma unroll
    for (int r = 0; r < 16; r++) oT[i][r] = 0.f;
  float m_ = -1e30f, l_ = 0.f;

  if (lo < hiT) {
    s16x8 qB[8];
#pragma unroll
    for (int hs = 0; hs < 8; hs++)
      qB[hs] = *(const s16x8*)(qb + (size_t)qg * Hn + hs * 16 + k8);
    s16x8 kA[2][8];
#pragma unroll
    for (int hs = 0; hs < 8; hs++)
      kA[0][hs] = *(const s16x8*)(kb + (size_t)(lo * 32 + l31) * Hn + hs * 16 + k8);

    auto body = [&](int t, auto CURC) {
      constexpr int CUR = decltype(CURC)::value;
      const int kvb = t * 32;
      s16x8 vA[8];
#pragma unroll
      for (int hs = 0; hs < 4; hs++)
#pragma unroll
        for (int c = 0; c < 2; c++)
          vA[hs * 2 + c] = *(const s16x8*)(vtb + (size_t)(hs * 32 + l31) * Tn + kvb + c * 16 + k8);
      const int tn = (t + 1 < hiT) ? t + 1 : t;
#pragma unroll
      for (int hs = 0; hs < 8; hs++)
        kA[CUR ^ 1][hs] = *(const s16x8*)(kb + (size_t)(tn * 32 + l31) * Hn + hs * 16 + k8);

      f32x16 sv;
#pragma unroll
      for (int r = 0; r < 16; r++) sv[r] = 0.f;
#pragma unroll
      for (int hs = 0; hs < 8; hs++)
        sv = __builtin_amdgcn_mfma_f32_32x32x16_bf16(kA[CUR][hs], qB[hs], sv, 0, 0, 0);

      if (t == qt) {
#pragma unroll
        for (int r = 0; r < 16; r++) {
          int kvg = kvb + (r & 3) + 8 * (r >> 2) + 4 * hi;
          if (kvg > qg) sv[r] = -1e30f;
        }
      }
      float om = sv[0];
#pragma unroll
      for (int r = 1; r < 16; r++) om = fmaxf(om, sv[r]);
      i32x2 mx = swap32(__builtin_bit_cast(int, om), __builtin_bit_cast(int, om));
      float pm = __builtin_bit_cast(float, hi ? mx[0] : mx[1]);
      float tmax = fmaxf(om, pm);
      if (__any(tmax > m_ + 8.f)) {
        float mn = fmaxf(m_, tmax);
        float sc = __expf(m_ - mn);
        m_ = mn; l_ *= sc;
#pragma unroll
        for (int i = 0; i < 4; i++)
#pragma unroll
          for (int r = 0; r < 16; r++) oT[i][r] *= sc;
      }
      float osum = 0.f;
#pragma unroll
      for (int r = 0; r < 16; r++) {
        sv[r] = __expf(sv[r] - m_);
        osum += sv[r];
      }
      i32x2 sx = swap32(__builtin_bit_cast(int, osum), __builtin_bit_cast(int, osum));
      float psum = __builtin_bit_cast(float, hi ? sx[0] : sx[1]);
      l_ += osum + psum;
      unsigned PK[8];
#pragma unroll
      for (int n = 0; n < 8; n++) PK[n] = cvtpk(sv[2 * n], sv[2 * n + 1]);
      i32x2 e0 = swap32((int)PK[0], (int)PK[2]);
      i32x2 e1 = swap32((int)PK[1], (int)PK[3]);
      i32x2 e2 = swap32((int)PK[4], (int)PK[6]);
      i32x2 e3 = swap32((int)PK[5], (int)PK[7]);
      i32x4 w0 = {e0[0], e1[0], e0[1], e1[1]};
      i32x4 w1 = {e2[0], e3[0], e2[1], e3[1]};
      s16x8 pB0 = __builtin_bit_cast(s16x8, w0);
      s16x8 pB1 = __builtin_bit_cast(s16x8, w1);
#pragma unroll
      for (int hs = 0; hs < 4; hs++) {
        oT[hs] = __builtin_amdgcn_mfma_f32_32x32x16_bf16(vA[hs * 2 + 0], pB0, oT[hs], 0, 0, 0);
        oT[hs] = __builtin_amdgcn_mfma_f32_32x32x16_bf16(vA[hs * 2 + 1], pB1, oT[hs], 0, 0, 0);
      }
    };

    for (int t = lo; t < hiT; t += 2) {
      body(t, std::integral_constant<int, 0>{});
      if (t + 1 < hiT) body(t + 1, std::integral_constant<int, 1>{});
    }
  }

  float* orow = o_part + (size_t)s * ((size_t)Mn * Hn) + (size_t)(b * Tn + qg) * Hn;
#pragma unroll
  for (int hs = 0; hs < 4; hs++)
#pragma unroll
    for (int g = 0; g < 4; g++) {
      f32x4 st = {oT[hs][4 * g + 0], oT[hs][4 * g + 1], oT[hs][4 * g + 2], oT[hs][4 * g + 3]};
      *(f32x4*)(orow + hs * 32 + g * 8 + hi * 4) = st;
    }
  if (lane < 32) {
    f32x2 w = {m_, l_};
    *(f32x2*)(ml + (size_t)s * (Mn * 2) + (size_t)(b * Tn + qg) * 2) = w;
  }
}

// ---------------------------------------------------------------------------
// Kernel 4: combine KV-split partials.
// ---------------------------------------------------------------------------
__global__ __launch_bounds__(256) void combine(const float* __restrict__ o_part,
                                               const float* __restrict__ ml,
                                               float* __restrict__ out, int S) {
  const int q = blockIdx.x * 2 + (threadIdx.x >> 7);
  const int h = threadIdx.x & 127;
  float M = -1e30f;
  for (int s = 0; s < S; s++) M = fmaxf(M, ml[(size_t)s * (Mn * 2) + q * 2]);
  float L = 0.f, acc = 0.f;
  for (int s = 0; s < S; s++) {
    float ms = ml[(size_t)s * (Mn * 2) + q * 2];
    float ls = ml[(size_t)s * (Mn * 2) + q * 2 + 1];
    float w = __expf(ms - M);
    L += ls * w;
    acc += o_part[(size_t)s * ((size_t)Mn * Hn) + (size_t)q * Hn + h] * w;
  }
  out[(size_t)q * Hn + h] = acc / L;
}

// ---------------------------------------------------------------------------
extern "C" void kernel_launch(void* const* d_in, const int* in_sizes, int n_in,
                              void* d_out, int out_size, void* d_ws, size_t ws_size,
                              hipStream_t stream) {
  const float* x  = (const float*)d_in[0];
  const float* Wk = (const float*)d_in[1];
  const float* Wq = (const float*)d_in[2];
  const float* Wv = (const float*)d_in[3];
  float* out = (float*)d_out;

  char* ws = (char*)d_ws;
  const size_t wt_b  = 786432;                      // 3*128*1024*2
  const size_t qkv_b = (size_t)3 * Mn * Hn * 2;     // 12.58 MB
  const size_t base  = wt_b + qkv_b;
  const size_t per   = (size_t)Mn * Hn * 4 + (size_t)Mn * 8;
  int sshift = (ws_size >= base + 4 * per) ? 2 : (ws_size >= base + 2 * per) ? 1 : 0;
  const int S = 1 << sshift;

  unsigned short* Wt  = (unsigned short*)ws;
  unsigned short* qkv = (unsigned short*)(ws + wt_b);
  float* o_part = (float*)(ws + base);
  float* mlp    = (float*)(ws + base + (size_t)S * Mn * Hn * 4);

  prep_wt<<<dim3(16, 4, 3), 256, 0, stream>>>(Wq, Wk, Wv, Wt);
  proj_fused<<<256, 512, 0, stream>>>(x, Wt, qkv);
  attn_fwd<<<64 * S * 8, 64, 0, stream>>>(qkv, o_part, mlp, sshift);
  combine<<<Mn / 2, 256, 0, stream>>>(o_part, mlp, out, S);
}

// Round 5
// 74.527 us; speedup vs baseline: 1.8427x; 1.2431x over previous
//
#include <hip/hip_runtime.h>
#include <type_traits>

// Shapes (fixed by the problem)
#define Bn 8
#define Tn 2048
#define Cn 1024
#define Hn 128
#define Mn (Bn*Tn)   // 16384

typedef __attribute__((ext_vector_type(4))) float f32x4;
typedef __attribute__((ext_vector_type(2))) float f32x2;
typedef __attribute__((ext_vector_type(16))) float f32x16;
typedef __attribute__((ext_vector_type(8))) short s16x8;
typedef __attribute__((ext_vector_type(4))) int i32x4;
typedef __attribute__((ext_vector_type(2))) int i32x2;
typedef unsigned int u32;

__device__ __forceinline__ unsigned short f2bf(float f) {
  union { float f; unsigned u; } v; v.f = f;
  unsigned r = v.u + 0x7FFFu + ((v.u >> 16) & 1u);   // RNE
  return (unsigned short)(r >> 16);
}

__device__ __forceinline__ unsigned cvtpk(float lo, float hi) {
  unsigned r;
  asm("v_cvt_pk_bf16_f32 %0, %1, %2" : "=v"(r) : "v"(lo), "v"(hi));
  return r;
}

// swap32(a,b): r0 = {a.lanes[0:31], b.lanes[0:31]}, r1 = {a.lanes[32:63], b.lanes[32:63]}
__device__ __forceinline__ i32x2 swap32(int a, int b) {
#if __has_builtin(__builtin_amdgcn_permlane32_swap)
  return __builtin_amdgcn_permlane32_swap(a, b, false, false);
#else
  int ax = __shfl_xor(a, 32), bx = __shfl_xor(b, 32);
  i32x2 r;
  r[0] = (threadIdx.x & 32) ? bx : a;
  r[1] = (threadIdx.x & 32) ? b : ax;
  return r;
#endif
}

__device__ __forceinline__ void gl_lds16(const void* g, void* l) {
  __builtin_amdgcn_global_load_lds((const __attribute__((address_space(1))) u32*)g,
                                   (__attribute__((address_space(3))) u32*)l, 16, 0, 0);
}

// ---------------------------------------------------------------------------
// Kernel 1: W [C,H] fp32 -> Wt [3][H][C] = [384][1024] bf16 (Wq scaled by 1/32)
// ---------------------------------------------------------------------------
__global__ __launch_bounds__(256) void prep_wt(const float* __restrict__ Wq,
                                               const float* __restrict__ Wk,
                                               const float* __restrict__ Wv,
                                               unsigned short* __restrict__ Wt) {
  __shared__ float tile[64][33];
  const int w = blockIdx.z;
  const float* W = (w == 0) ? Wq : (w == 1) ? Wk : Wv;
  const float scale = (w == 0) ? 0.03125f : 1.0f;   // C^-0.5 folded into Wq (exact pow2)
  const int c0 = blockIdx.x * 64, h0 = blockIdx.y * 32;
  const int tid = threadIdx.x;
  const int hl = tid & 31, cg = tid >> 5;
#pragma unroll
  for (int i = 0; i < 8; i++) {
    int cl = cg * 8 + i;
    tile[cl][hl] = W[(c0 + cl) * Hn + h0 + hl];
  }
  __syncthreads();
  const int cl2 = tid & 63, hg = tid >> 6;
#pragma unroll
  for (int i = 0; i < 8; i++) {
    int hl2 = hg * 8 + i;
    Wt[(size_t)(w * Hn + h0 + hl2) * Cn + c0 + cl2] = f2bf(tile[cl2][hl2] * scale);
  }
}

// ---------------------------------------------------------------------------
// Kernel 2: FUSED QKV projection (unchanged from round 4).
// ---------------------------------------------------------------------------
__global__ __launch_bounds__(512, 2) void proj_fused(const float* __restrict__ x,
                                                     const unsigned short* __restrict__ Wt,
                                                     unsigned short* __restrict__ qkv) {
  __shared__ __align__(16) unsigned short Abuf[2][64 * 64];    // 16 KB
  __shared__ __align__(16) unsigned short Bbuf[2][384 * 64];   // 96 KB
  const int tid = threadIdx.x;
  const int lane = tid & 63, wv = tid >> 6;   // 8 waves
  const int wm = wv >> 2, wn = wv & 3;
  const int l31 = lane & 31, hi = lane >> 5;
  const int bm = blockIdx.x * 64;

  const int ar = tid >> 3;
  const int as = (tid & 7) ^ (ar & 7);

  f32x16 acc[3];
#pragma unroll
  for (int i = 0; i < 3; i++)
#pragma unroll
    for (int r = 0; r < 16; r++) acc[i][r] = 0.f;

  auto stageB = [&](int buf, int kk) {
#pragma unroll
    for (int i = 0; i < 6; i++) {
      int r0 = wv * 48 + i * 8;
      int n = r0 + (lane >> 3);
      const unsigned short* src = Wt + (size_t)n * Cn + kk + (((lane & 7) ^ (n & 7)) << 3);
      gl_lds16(src, &Bbuf[buf][r0 * 64]);
    }
  };
  auto loadA = [&](int kk, float4& v0, float4& v1) {
    const float* g = x + (size_t)(bm + ar) * Cn + kk + as * 8;
    v0 = *(const float4*)g;
    v1 = *(const float4*)(g + 4);
  };
  auto writeA = [&](int buf, float4 v0, float4 v1) {
    i32x4 w = {(int)cvtpk(v0.x, v0.y), (int)cvtpk(v0.z, v0.w),
               (int)cvtpk(v1.x, v1.y), (int)cvtpk(v1.z, v1.w)};
    *(i32x4*)&Abuf[buf][ar * 64 + ((tid & 7) << 3)] = w;
  };

  {
    float4 a0, a1;
    loadA(0, a0, a1);
    stageB(0, 0);
    writeA(0, a0, a1);
  }
  __syncthreads();

#pragma unroll 2
  for (int t = 0; t < 16; t++) {
    const int cur = t & 1, nxt = cur ^ 1;
    const bool more = (t < 15);
    float4 a0, a1;
    if (more) {
      loadA((t + 1) * 64, a0, a1);
      stageB(nxt, (t + 1) * 64);
    }
    const unsigned short* Ab = Abuf[cur];
    const unsigned short* Bb = Bbuf[cur];
    s16x8 aF[4];
    const int arow = wm * 32 + l31;
#pragma unroll
    for (int ks = 0; ks < 4; ks++)
      aF[ks] = *(const s16x8*)&Ab[arow * 64 + (((ks * 2 + hi) ^ (arow & 7)) << 3)];
#pragma unroll
    for (int ks = 0; ks < 4; ks++)
#pragma unroll
      for (int ni = 0; ni < 3; ni++) {
        int brow = (wn * 3 + ni) * 32 + l31;
        s16x8 bF = *(const s16x8*)&Bb[brow * 64 + (((ks * 2 + hi) ^ (brow & 7)) << 3)];
        acc[ni] = __builtin_amdgcn_mfma_f32_32x32x16_bf16(aF[ks], bF, acc[ni], 0, 0, 0);
      }
    if (more) {
      writeA(nxt, a0, a1);
      __syncthreads();
    }
  }

#pragma unroll
  for (int ni = 0; ni < 3; ni++) {
    const int nt = wn * 3 + ni;
    if (nt < 8) {
      const int w = nt >> 2;
      const int h = (nt & 3) * 32 + l31;
      unsigned short* o = qkv + (size_t)w * ((size_t)Mn * Hn);
#pragma unroll
      for (int r = 0; r < 16; r++) {
        int m = bm + wm * 32 + (r & 3) + 8 * (r >> 2) + 4 * hi;
        o[(size_t)m * Hn + h] = f2bf(acc[ni][r]);
      }
    } else {
      const int h = (nt - 8) * 32 + l31;
      const int bb = bm >> 11;
      const int tl0 = (bm & 2047) + wm * 32;
      unsigned short* vt = qkv + (size_t)2 * Mn * Hn + (size_t)bb * (Hn * Tn) + (size_t)h * Tn;
#pragma unroll
      for (int r = 0; r < 16; r++)
        vt[tl0 + (r & 3) + 8 * (r >> 2) + 4 * hi] = f2bf(acc[ni][r]);
    }
  }
}

// ---------------------------------------------------------------------------
// Kernel 3: causal flash attention. 4 waves/block, 128 q-rows/block (32/wave),
// KVBLK=64 staged in LDS (XOR-swizzled, global_load_lds, double-buffered,
// 2-phase). Swapped 32x32 MFMA, in-register softmax. KV-split S chunks with
// complementary q-tile pairing for load balance. Partials to workspace.
// ---------------------------------------------------------------------------
__global__ __launch_bounds__(256, 2) void attn_fwd(const unsigned short* __restrict__ qkv,
                                                   float* __restrict__ o_part,
                                                   float* __restrict__ ml,
                                                   int sshift) {
  __shared__ __align__(16) unsigned short Kl[2][64 * 128];  // [kv][h] 16KB x2
  __shared__ __align__(16) unsigned short Vl[2][128 * 64];  // [h][kv] 16KB x2

  const int bid = blockIdx.x;
  const int b = bid & 7;                    // batch -> XCD pin
  const int r = bid >> 3;
  const int jj = r & 15;
  const int sp = r >> 4;
  const int S = 1 << sshift;
  const int j = (S > 1 && sp >= (S >> 1)) ? (15 - jj) : jj;   // complementary pairing
  const int s = sp;

  const int tid = threadIdx.x;
  const int lane = tid & 63, wv = tid >> 6;   // 4 waves
  const int l31 = lane & 31, hi = lane >> 5;

  const unsigned short* qb  = qkv + (size_t)b * (Tn * Hn);
  const unsigned short* kb  = qkv + (size_t)(Mn * Hn) + (size_t)b * (Tn * Hn);
  const unsigned short* vtb = qkv + (size_t)2 * (Mn * Hn) + (size_t)b * (Hn * Tn);

  const int qrow0 = j * 128 + wv * 32;      // this wave's 32 q-rows
  const int qg = qrow0 + l31;               // this lane's q-row

  const int ntt = (j + 1) * 2;              // kv tiles of 64 for this q-tile
  const int tlo = (s * ntt) >> sshift;
  const int thi = ((s + 1) * ntt) >> sshift;

  f32x16 oT[4];
#pragma unroll
  for (int i = 0; i < 4; i++)
#pragma unroll
    for (int q = 0; q < 16; q++) oT[i][q] = 0.f;
  float m_ = -1e30f, l_ = 0.f;

  auto stage = [&](int buf, int tile) {
    const int kvb0 = tile * 64;
    // K [64 kv][16 chunks of 16B], 4 insts/wave, pre-swizzled source
#pragma unroll
    for (int i = 0; i < 4; i++) {
      int r0 = wv * 16 + i * 4;
      int row = r0 + (lane >> 4);
      int ch = lane & 15;
      const unsigned short* src = kb + (size_t)(kvb0 + row) * Hn + ((ch ^ (row & 7)) << 3);
      gl_lds16(src, &Kl[buf][r0 * 128]);
    }
    // V^T [128 h][8 chunks of 16B], 4 insts/wave
#pragma unroll
    for (int i = 0; i < 4; i++) {
      int r0 = wv * 32 + i * 8;
      int row = r0 + (lane >> 3);
      int ch = lane & 7;
      const unsigned short* src = vtb + (size_t)row * Tn + kvb0 + ((ch ^ (row & 7)) << 3);
      gl_lds16(src, &Vl[buf][r0 * 64]);
    }
  };

  if (tlo < thi) {
    // Q B-fragments: n=q=l31, k = hs*16 + hi*8 + jx
    s16x8 qB[8];
#pragma unroll
    for (int hs = 0; hs < 8; hs++)
      qB[hs] = *(const s16x8*)(qb + (size_t)qg * Hn + hs * 16 + hi * 8);

    stage(0, tlo);
    asm volatile("s_waitcnt vmcnt(0)");
    __syncthreads();
    int buf = 0;

    for (int t = tlo; t < thi; t++) {
      if (t + 1 < thi) stage(buf ^ 1, t + 1);   // loads in flight over compute
      const int kvb = t * 64;
      if (kvb < qrow0 + 32) {                   // wave not fully above diagonal
        const unsigned short* Kb = &Kl[buf][0];
        const unsigned short* Vb = &Vl[buf][0];
        // ---- S^T = K Q^T (two 32-kv halves) ----
        f32x16 sv0, sv1;
#pragma unroll
        for (int q = 0; q < 16; q++) { sv0[q] = 0.f; sv1[q] = 0.f; }
        __builtin_amdgcn_s_setprio(1);
        {
          const int row = l31;
#pragma unroll
          for (int hs = 0; hs < 8; hs++) {
            s16x8 kf = *(const s16x8*)&Kb[row * 128 + (((hs * 2 + hi) ^ (row & 7)) << 3)];
            sv0 = __builtin_amdgcn_mfma_f32_32x32x16_bf16(kf, qB[hs], sv0, 0, 0, 0);
          }
        }
        {
          const int row = 32 + l31;
#pragma unroll
          for (int hs = 0; hs < 8; hs++) {
            s16x8 kf = *(const s16x8*)&Kb[row * 128 + (((hs * 2 + hi) ^ (row & 7)) << 3)];
            sv1 = __builtin_amdgcn_mfma_f32_32x32x16_bf16(kf, qB[hs], sv1, 0, 0, 0);
          }
        }
        __builtin_amdgcn_s_setprio(0);
        // ---- causal mask (diagonal-adjacent tiles only) ----
        if (kvb + 63 > qrow0) {
#pragma unroll
          for (int q = 0; q < 16; q++) {
            int kr = (q & 3) + 8 * (q >> 2) + 4 * hi;
            if (kvb + kr > qg) sv0[q] = -1e30f;
            if (kvb + 32 + kr > qg) sv1[q] = -1e30f;
          }
        }
        // ---- online softmax (row = per-lane) ----
        float om = sv0[0];
#pragma unroll
        for (int q = 1; q < 16; q++) om = fmaxf(om, sv0[q]);
#pragma unroll
        for (int q = 0; q < 16; q++) om = fmaxf(om, sv1[q]);
        i32x2 mx = swap32(__builtin_bit_cast(int, om), __builtin_bit_cast(int, om));
        float pm = __builtin_bit_cast(float, hi ? mx[0] : mx[1]);
        float tmax = fmaxf(om, pm);
        if (__any(tmax > m_ + 8.f)) {           // deferred rescale (T13)
          float mn = fmaxf(m_, tmax);
          float sc = __expf(m_ - mn);
          m_ = mn; l_ *= sc;
#pragma unroll
          for (int i = 0; i < 4; i++)
#pragma unroll
            for (int q = 0; q < 16; q++) oT[i][q] *= sc;
        }
        float osum = 0.f;
#pragma unroll
        for (int q = 0; q < 16; q++) { sv0[q] = __expf(sv0[q] - m_); osum += sv0[q]; }
#pragma unroll
        for (int q = 0; q < 16; q++) { sv1[q] = __expf(sv1[q] - m_); osum += sv1[q]; }
        i32x2 sx = swap32(__builtin_bit_cast(int, osum), __builtin_bit_cast(int, osum));
        float psum = __builtin_bit_cast(float, hi ? sx[0] : sx[1]);
        l_ += osum + psum;
        // ---- pack P^T to bf16 B-fragments (T12) ----
        s16x8 pB[4];
        {
          unsigned PK[8];
#pragma unroll
          for (int n = 0; n < 8; n++) PK[n] = cvtpk(sv0[2 * n], sv0[2 * n + 1]);
          i32x2 e0 = swap32((int)PK[0], (int)PK[2]);
          i32x2 e1 = swap32((int)PK[1], (int)PK[3]);
          i32x2 e2 = swap32((int)PK[4], (int)PK[6]);
          i32x2 e3 = swap32((int)PK[5], (int)PK[7]);
          i32x4 w0 = {e0[0], e1[0], e0[1], e1[1]};
          i32x4 w1 = {e2[0], e3[0], e2[1], e3[1]};
          pB[0] = __builtin_bit_cast(s16x8, w0);
          pB[1] = __builtin_bit_cast(s16x8, w1);
        }
        {
          unsigned PK[8];
#pragma unroll
          for (int n = 0; n < 8; n++) PK[n] = cvtpk(sv1[2 * n], sv1[2 * n + 1]);
          i32x2 e0 = swap32((int)PK[0], (int)PK[2]);
          i32x2 e1 = swap32((int)PK[1], (int)PK[3]);
          i32x2 e2 = swap32((int)PK[4], (int)PK[6]);
          i32x2 e3 = swap32((int)PK[5], (int)PK[7]);
          i32x4 w0 = {e0[0], e1[0], e0[1], e1[1]};
          i32x4 w1 = {e2[0], e3[0], e2[1], e3[1]};
          pB[2] = __builtin_bit_cast(s16x8, w0);
          pB[3] = __builtin_bit_cast(s16x8, w1);
        }
        // ---- O^T += V^T P^T ----
        __builtin_amdgcn_s_setprio(1);
#pragma unroll
        for (int hsl = 0; hsl < 4; hsl++) {
          const int row = hsl * 32 + l31;
#pragma unroll
          for (int ks = 0; ks < 4; ks++) {
            s16x8 vf = *(const s16x8*)&Vl[buf][row * 64 + (((ks * 2 + hi) ^ (row & 7)) << 3)];
            oT[hsl] = __builtin_amdgcn_mfma_f32_32x32x16_bf16(vf, pB[ks], oT[hsl], 0, 0, 0);
          }
        }
        __builtin_amdgcn_s_setprio(0);
      }
      asm volatile("s_waitcnt vmcnt(0)");       // staged t+1 landed
      __syncthreads();                          // cur fully consumed by all waves
      buf ^= 1;
    }
  }

  // epilogue: o_part[s][row][h], h = hsl*32 + (q&3) + 8*(q>>2) + 4*hi
  float* orow = o_part + (size_t)s * ((size_t)Mn * Hn) + (size_t)(b * Tn + qg) * Hn;
#pragma unroll
  for (int hsl = 0; hsl < 4; hsl++)
#pragma unroll
    for (int g = 0; g < 4; g++) {
      f32x4 st = {oT[hsl][4 * g + 0], oT[hsl][4 * g + 1], oT[hsl][4 * g + 2], oT[hsl][4 * g + 3]};
      *(f32x4*)(orow + hsl * 32 + g * 8 + hi * 4) = st;
    }
  if (lane < 32) {
    f32x2 w = {m_, l_};
    *(f32x2*)(ml + (size_t)s * (Mn * 2) + (size_t)(b * Tn + qg) * 2) = w;
  }
}

// ---------------------------------------------------------------------------
// Kernel 4: combine KV-split partials.
// ---------------------------------------------------------------------------
__global__ __launch_bounds__(256) void combine(const float* __restrict__ o_part,
                                               const float* __restrict__ ml,
                                               float* __restrict__ out, int S) {
  const int q = blockIdx.x * 2 + (threadIdx.x >> 7);
  const int h = threadIdx.x & 127;
  float M = -1e30f;
  for (int s = 0; s < S; s++) M = fmaxf(M, ml[(size_t)s * (Mn * 2) + q * 2]);
  float L = 0.f, acc = 0.f;
  for (int s = 0; s < S; s++) {
    float ms = ml[(size_t)s * (Mn * 2) + q * 2];
    float ls = ml[(size_t)s * (Mn * 2) + q * 2 + 1];
    float w = __expf(ms - M);
    L += ls * w;
    acc += o_part[(size_t)s * ((size_t)Mn * Hn) + (size_t)q * Hn + h] * w;
  }
  out[(size_t)q * Hn + h] = acc / L;
}

// ---------------------------------------------------------------------------
extern "C" void kernel_launch(void* const* d_in, const int* in_sizes, int n_in,
                              void* d_out, int out_size, void* d_ws, size_t ws_size,
                              hipStream_t stream) {
  const float* x  = (const float*)d_in[0];
  const float* Wk = (const float*)d_in[1];
  const float* Wq = (const float*)d_in[2];
  const float* Wv = (const float*)d_in[3];
  float* out = (float*)d_out;

  char* ws = (char*)d_ws;
  const size_t wt_b  = 786432;                      // 3*128*1024*2
  const size_t qkv_b = (size_t)3 * Mn * Hn * 2;     // 12.58 MB
  const size_t base  = wt_b + qkv_b;
  const size_t per   = (size_t)Mn * Hn * 4 + (size_t)Mn * 8;
  int sshift = (ws_size >= base + 4 * per) ? 2 : (ws_size >= base + 2 * per) ? 1 : 0;
  const int S = 1 << sshift;

  unsigned short* Wt  = (unsigned short*)ws;
  unsigned short* qkv = (unsigned short*)(ws + wt_b);
  float* o_part = (float*)(ws + base);
  float* mlp    = (float*)(ws + base + (size_t)S * Mn * Hn * 4);

  prep_wt<<<dim3(16, 4, 3), 256, 0, stream>>>(Wq, Wk, Wv, Wt);
  proj_fused<<<256, 512, 0, stream>>>(x, Wt, qkv);
  attn_fwd<<<128 * S, 256, 0, stream>>>(qkv, o_part, mlp, sshift);
  combine<<<Mn / 2, 256, 0, stream>>>(o_part, mlp, out, S);
}